// Round 22
// baseline (654.505 us; speedup 1.0000x reference)
//
#include <hip/hip_runtime.h>
#include <hip/hip_bf16.h>
#include <math.h>

#define N_NODES 40000
#define N_EDGES 640000
#define DIM     128
#define HEADS   8
#define DHEAD   16
#define LAYERS  3
#define IN_DIM  64
#define FF_DIM  218
#define BN_EPS  1e-5f
#define NEG_SLOPE 0.2f
#define INV_N   (1.f / N_NODES)
#define NREP    128
#define AGG_NPW 2                      // nodes per wave in aggregate
#define AGG_BLOCKS (N_NODES / (4 * AGG_NPW))   // 5000
#define SEG     1000                   // CSR scan segment
#define NSEG    40                     // N_NODES / SEG

typedef __attribute__((ext_vector_type(8))) short  bhalf8;
typedef __attribute__((ext_vector_type(4))) float  floatx4;
typedef __attribute__((ext_vector_type(4))) int    intx4;

__device__ __forceinline__ unsigned bfpack2(float a, float b) {
    unsigned ua = __float_as_uint(a);
    ua = ua + 0x7FFFu + ((ua >> 16) & 1u);
    unsigned ub = __float_as_uint(b);
    ub = ub + 0x7FFFu + ((ub >> 16) & 1u);
    return (ua >> 16) | (ub & 0xFFFF0000u);
}
__device__ __forceinline__ unsigned short bf16of(float a) {
    unsigned ua = __float_as_uint(a);
    ua = ua + 0x7FFFu + ((ua >> 16) & 1u);
    return (unsigned short)(ua >> 16);
}
__device__ __forceinline__ float bf2f(unsigned short u) {
    return __uint_as_float(((unsigned)u) << 16);
}
__device__ __forceinline__ float bflo(unsigned u) { return __uint_as_float(u << 16); }
__device__ __forceinline__ float bfhi(unsigned u) { return __uint_as_float(u & 0xFFFF0000u); }
__device__ __forceinline__ float rsum16(float v) {
    v += __shfl_xor(v, 1, 16);
    v += __shfl_xor(v, 2, 16);
    v += __shfl_xor(v, 4, 16);
    v += __shfl_xor(v, 8, 16);
    return v;
}

// packed weight layout offsets (bf16 elements)
#define OFF_EMB 0
#define OFF_GAT 8192
#define OFF_W1  57344
#define OFF_W2  143360
#define OFF_DEC 229376
#define WPK_TOT 294912
#define HIST_BLOCKS ((N_EDGES + 255) / 256)
#define PACK_BLOCKS ((WPK_TOT + 255) / 256)

// ---------------------------------------------------------------- hist + weight pre-pack (merged)
__global__ void hist_pack_kernel(const int* __restrict__ dst, int* __restrict__ counts,
                                 const float* __restrict__ W_emb,
                                 const float* __restrict__ gat_W,
                                 const float* __restrict__ ff_W1,
                                 const float* __restrict__ ff_W2,
                                 const float* __restrict__ dec_W1,
                                 unsigned short* __restrict__ wpk) {
    int bid = blockIdx.x;
    if (bid < HIST_BLOCKS) {
        int e = bid * 256 + threadIdx.x;
        if (e < N_EDGES) atomicAdd(&counts[dst[e]], 1);
        return;
    }
    int i = (bid - HIST_BLOCKS) * 256 + threadIdx.x;
    if (i >= WPK_TOT) return;
    int o = i;
    if (o < 8192) {                       // emb: [128][64]
        int n = o >> 6, k = o & 63;
        wpk[OFF_EMB + o] = bf16of(W_emb[k * 128 + n]);
        return;
    }
    o -= 8192;
    if (o < 3 * 16384) {                  // gat: [l][128][128]
        int l = o >> 14, r = o & 16383;
        int n = r >> 7, k = r & 127;
        wpk[OFF_GAT + o] = bf16of(gat_W[l * 16384 + k * 128 + n]);
        return;
    }
    o -= 3 * 16384;
    if (o < 3 * 28672) {                  // W1: [l][224][128]
        int l = o / 28672, r = o % 28672;
        int n = r >> 7, k = r & 127;
        float v = (n < FF_DIM) ? ff_W1[(size_t)l * 128 * FF_DIM + k * FF_DIM + n] : 0.f;
        wpk[OFF_W1 + o] = bf16of(v);
        return;
    }
    o -= 3 * 28672;
    if (o < 3 * 28672) {                  // W2: [l][128][224]
        int l = o / 28672, r = o % 28672;
        int n = r / 224, k = r % 224;
        float v = (k < FF_DIM) ? ff_W2[(size_t)l * FF_DIM * 128 + k * 128 + n] : 0.f;
        wpk[OFF_W2 + o] = bf16of(v);
        return;
    }
    o -= 3 * 28672;
    {                                     // dec: [128][512]
        int n = o >> 9, k = o & 511;
        wpk[OFF_DEC + o] = bf16of(dec_W1[k * 128 + n]);
    }
}

// ---------------------------------------------------------------- CSR build (R14, measured -49us)
// 3-phase reduce-then-scan replaced the 64.7us single-block scan (0.13% occ).
__global__ void seg_reduce_kernel(const int* __restrict__ counts, int* __restrict__ partials) {
    __shared__ int wsum[4];
    int b = blockIdx.x, tid = threadIdx.x;
    int s = 0;
    for (int i = tid; i < SEG; i += 256) {
        int idx = b * SEG + i;
        if (idx < N_NODES) s += counts[idx];
    }
    #pragma unroll
    for (int o = 32; o > 0; o >>= 1) s += __shfl_down(s, o);
    if ((tid & 63) == 0) wsum[tid >> 6] = s;
    __syncthreads();
    if (tid == 0) partials[b] = (wsum[0] + wsum[1]) + (wsum[2] + wsum[3]);
}

__global__ void seg_offset_kernel(const int* __restrict__ partials, int* __restrict__ offs,
                                  int* __restrict__ indptr) {
    int lane = threadIdx.x;
    int p = (lane < NSEG) ? partials[lane] : 0;
    int v = p;
    #pragma unroll
    for (int d = 1; d < 64; d <<= 1) {
        int t = __shfl_up(v, d);
        if (lane >= d) v += t;
    }
    if (lane < NSEG) offs[lane] = v - p;         // exclusive
    if (lane == NSEG - 1) indptr[N_NODES] = v;   // grand total
}

__global__ __launch_bounds__(1024) void seg_scan_kernel(const int* __restrict__ counts,
                                                        const int* __restrict__ offs,
                                                        int* __restrict__ indptr,
                                                        int* __restrict__ cursor) {
    __shared__ int tsum[1024];
    int b = blockIdx.x, tid = threadIdx.x;
    int idx = b * SEG + tid;
    int v = (tid < SEG && idx < N_NODES) ? counts[idx] : 0;
    tsum[tid] = v;
    __syncthreads();
    for (int o = 1; o < 1024; o <<= 1) {
        int t = (tid >= o) ? tsum[tid - o] : 0;
        __syncthreads();
        tsum[tid] += t;
        __syncthreads();
    }
    if (tid < SEG && idx < N_NODES) {
        int e = offs[b] + tsum[tid] - v;   // exclusive + segment offset
        indptr[idx] = e;
        cursor[idx] = e;
    }
}

__global__ void scatter_kernel(const int* __restrict__ src, const int* __restrict__ dst,
                               int* __restrict__ cursor,
                               int* __restrict__ srcs_csr) {
    int e = blockIdx.x * blockDim.x + threadIdx.x;
    if (e < N_EDGES) {
        int d = dst[e];
        int pos = atomicAdd(&cursor[d], 1);
        srcs_csr[pos] = src[e];
    }
}

// ---------------------------------------------------------------- L2-resident-B GEMM
// R21 measured (651.9us): dec = 61us @ 878 GB/s, PD=4 ring = 3 A-steps in
// flight/wave. R22: PD 4->8 — the whole 8-step chunk's A-stream is issued
// up front; vmcnt ordering retires loads oldest-first = strictly in
// consumption order, so 7 stay in flight. +16 VGPR (ap[8]), LDS unchanged.
// Only dec instantiates BLDS; all other dispatches byte-identical.
// AMODE: 0 none; 1 BN affine on A; 2 dec512 layered affine; 3 NREP-replica stats.
template<int NT, int KPAD, int AMODE, bool ABF16, int MT, bool ELER, bool RESBF, bool BLDS>
__global__ __launch_bounds__(256) void gemm_l2_kernel(
    const float* __restrict__ A, const unsigned short* __restrict__ Abf, int lda,
    const unsigned short* __restrict__ Bpk,
    const float* __restrict__ bias,
    const void* __restrict__ resv, int ldres,
    const float* __restrict__ res_stats, const float* __restrict__ res_g,
    const float* __restrict__ res_b,
    float* __restrict__ C, unsigned short* __restrict__ Cbf, int ldc,
    float* __restrict__ out_stats,
    int M, int Nact, int relu,
    const float* __restrict__ a_stats, float* __restrict__ a_stats_out,
    const float* __restrict__ a_g, const float* __restrict__ a_b,
    const float* __restrict__ al, const float* __restrict__ ar,
    float* __restrict__ el_out, float* __restrict__ er_out)
{
    constexpr int SCN = (AMODE > 0) ? KPAD : 1;
    constexpr int BROWS = 64 * MT;
    constexpr int STEPS = KPAD / 32;
    constexpr int KCH = (KPAD > 256) ? 256 : KPAD;   // B-stage chunk (elements)
    constexpr int BPKC = KCH + 8;                    // padded LDS row (odd 16B-slot stride)
    __shared__ float sc_s[SCN];
    __shared__ float sh_s[SCN];
    __shared__ float st_sum[128];
    __shared__ float st_sq[128];
    __shared__ float el_s[ELER ? BROWS : 1][ELER ? NT : 1];
    __shared__ float er_s[ELER ? BROWS : 1][ELER ? NT : 1];
    __shared__ unsigned short Bs[(BLDS && ABF16) ? NT * 16 * BPKC : 1];

    int tid = threadIdx.x, wave = tid >> 6, lane = tid & 63;
    int q = lane >> 4, tl = lane & 15;
    int colbase = blockIdx.y * (NT * 16);
    int row0b = blockIdx.x * BROWS;
    int rowtile = row0b + wave * (MT * 16);

    if constexpr (AMODE == 1 || AMODE == 2) {
        for (int idx = tid; idx < KPAD; idx += 256) {
            float scv = 1.f, shv = 0.f;
            if constexpr (AMODE == 1) {
                float mu = a_stats[idx] * INV_N;
                float var = a_stats[128 + idx] * INV_N - mu * mu;
                scv = a_g[idx] * rsqrtf(var + BN_EPS);
                shv = a_b[idx] - mu * scv;
            } else {
                int l = idx >> 7;
                if (l > 0) {
                    int c = idx & 127;
                    const float* st = a_stats + (l - 1) * 256;
                    float mu = st[c] * INV_N;
                    float var = st[128 + c] * INV_N - mu * mu;
                    scv = a_g[(l - 1) * 128 + c] * rsqrtf(var + BN_EPS);
                    shv = a_b[(l - 1) * 128 + c] - mu * scv;
                }
            }
            sc_s[idx] = scv;
            sh_s[idx] = shv;
        }
        __syncthreads();
    }
    if constexpr (AMODE == 3) {
        for (int idx = tid; idx < 128; idx += 256) {
            float s = 0.f, sq = 0.f;
            #pragma unroll 8
            for (int r = 0; r < NREP; r++) {
                s  += a_stats[r * 256 + idx];
                sq += a_stats[r * 256 + 128 + idx];
            }
            a_stats_out[idx] = s;            // benign identical-value race
            a_stats_out[128 + idx] = sq;
            float mu = s * INV_N;
            float var = sq * INV_N - mu * mu;
            float scv = a_g[idx] * rsqrtf(var + BN_EPS);
            sc_s[idx] = scv;
            sh_s[idx] = a_b[idx] - mu * scv;
        }
        __syncthreads();
    }

    int rowm[MT];
    bool vrm[MT];
    #pragma unroll
    for (int mt = 0; mt < MT; mt++) {
        rowm[mt] = rowtile + mt * 16 + tl;
        vrm[mt] = rowm[mt] < M;
    }
    const unsigned short* bp = Bpk + (size_t)colbase * KPAD;

    floatx4 acc[MT][NT] = {};

    if constexpr (BLDS && ABF16) {
        constexpr int NCH = KPAD / KCH;
        constexpr int CSTEPS = KCH / 32;
        constexpr int PD = (CSTEPS >= 8) ? 8 : CSTEPS;   // R22: 4->8 deep A-ring
        for (int ch = 0; ch < NCH; ch++) {
            const int kbase = ch * KCH;
            // stage this K-chunk of the B panel -> LDS (coalesced 16B/lane)
            for (int idx = tid; idx < NT * 16 * (KCH / 8); idx += 256) {
                int col = idx / (KCH / 8), k8 = idx % (KCH / 8);
                *(intx4*)(Bs + col * BPKC + k8 * 8) =
                    *(const intx4*)(bp + (size_t)col * KPAD + kbase + k8 * 8);
            }
            __syncthreads();
            // A-ring: PD-1 steps in flight; B via ds_read (independent lgkmcnt)
            intx4 ap[PD][MT];
            #pragma unroll
            for (int s = 0; s < PD - 1; s++) {
                int gk = kbase + s * 32 + q * 8;
                #pragma unroll
                for (int mt = 0; mt < MT; mt++) {
                    intx4 u = {};
                    if (vrm[mt]) u = *(const intx4*)(Abf + (size_t)rowm[mt] * lda + gk);
                    ap[s][mt] = u;
                }
            }
            #pragma unroll
            for (int s = 0; s < CSTEPS; s++) {
                int lk = s * 32 + q * 8;
                int gk = kbase + lk;
                if (s + PD - 1 < CSTEPS) {
                    int gk2 = kbase + (s + PD - 1) * 32 + q * 8;
                    #pragma unroll
                    for (int mt = 0; mt < MT; mt++) {
                        intx4 u = {};
                        if (vrm[mt]) u = *(const intx4*)(Abf + (size_t)rowm[mt] * lda + gk2);
                        ap[(s + PD - 1) % PD][mt] = u;
                    }
                }
                bhalf8 breg[NT];
                #pragma unroll
                for (int j = 0; j < NT; j++)
                    breg[j] = *(const bhalf8*)(Bs + (j * 16 + tl) * BPKC + lk);
                bhalf8 af[MT];
                #pragma unroll
                for (int mt = 0; mt < MT; mt++) {
                    intx4 u = ap[s % PD][mt];
                    if constexpr (AMODE > 0) {
                        #pragma unroll
                        for (int w = 0; w < 4; w++) {
                            unsigned uw = (unsigned)u[w];
                            float lo = bflo(uw), hi = bfhi(uw);
                            lo = fmaf(sc_s[gk + 2 * w],     lo, sh_s[gk + 2 * w]);
                            hi = fmaf(sc_s[gk + 2 * w + 1], hi, sh_s[gk + 2 * w + 1]);
                            u[w] = (int)bfpack2(lo, hi);
                        }
                    }
                    af[mt] = *(bhalf8*)&u;
                }
                #pragma unroll
                for (int mt = 0; mt < MT; mt++)
                    #pragma unroll
                    for (int j = 0; j < NT; j++)
                        acc[mt][j] = __builtin_amdgcn_mfma_f32_16x16x32_bf16(af[mt], breg[j], acc[mt][j], 0, 0, 0);
            }
            __syncthreads();   // protect Bs before next chunk's restage
        }
    } else {
        // R5 direct path (measured-best for short K): CST=2 grouped loads
        constexpr int CST = (STEPS > 2) ? 2 : STEPS;
        #pragma unroll
        for (int c0 = 0; c0 < STEPS; c0 += CST) {
            intx4  arawb[CST][MT];
            floatx4 araw0[ABF16 ? 1 : CST][ABF16 ? 1 : MT];
            floatx4 araw1[ABF16 ? 1 : CST][ABF16 ? 1 : MT];
            bhalf8 breg[CST][NT];
            #pragma unroll
            for (int cs = 0; cs < CST; cs++) {
                if (c0 + cs >= STEPS) continue;
                int gk = (c0 + cs) * 32 + q * 8;
                #pragma unroll
                for (int j = 0; j < NT; j++)
                    breg[cs][j] = *(const bhalf8*)(bp + (size_t)(j * 16 + tl) * KPAD + gk);
                #pragma unroll
                for (int mt = 0; mt < MT; mt++) {
                    if constexpr (ABF16) {
                        intx4 u = {};
                        if (vrm[mt]) u = *(const intx4*)(Abf + (size_t)rowm[mt] * lda + gk);
                        arawb[cs][mt] = u;
                    } else {
                        floatx4 x0 = {}, x1 = {};
                        if (vrm[mt]) {
                            const float* apt = A + (size_t)rowm[mt] * lda + gk;
                            x0 = *(const floatx4*)apt;
                            x1 = *(const floatx4*)(apt + 4);
                        }
                        araw0[cs][mt] = x0;
                        araw1[cs][mt] = x1;
                    }
                }
            }
            #pragma unroll
            for (int cs = 0; cs < CST; cs++) {
                if (c0 + cs >= STEPS) continue;
                int gk = (c0 + cs) * 32 + q * 8;
                bhalf8 af[MT];
                #pragma unroll
                for (int mt = 0; mt < MT; mt++) {
                    if constexpr (ABF16) {
                        intx4 u = arawb[cs][mt];
                        if constexpr (AMODE > 0) {
                            #pragma unroll
                            for (int w = 0; w < 4; w++) {
                                unsigned uw = (unsigned)u[w];
                                float lo = bflo(uw), hi = bfhi(uw);
                                lo = fmaf(sc_s[gk + 2 * w],     lo, sh_s[gk + 2 * w]);
                                hi = fmaf(sc_s[gk + 2 * w + 1], hi, sh_s[gk + 2 * w + 1]);
                                u[w] = (int)bfpack2(lo, hi);
                            }
                        }
                        af[mt] = *(bhalf8*)&u;
                    } else {
                        floatx4 x0 = araw0[cs][mt], x1 = araw1[cs][mt];
                        if constexpr (AMODE > 0) {
                            #pragma unroll
                            for (int jj = 0; jj < 4; jj++) {
                                x0[jj] = fmaf(sc_s[gk + jj],     x0[jj], sh_s[gk + jj]);
                                x1[jj] = fmaf(sc_s[gk + 4 + jj], x1[jj], sh_s[gk + 4 + jj]);
                            }
                        }
                        intx4 t = intx4{(int)bfpack2(x0[0], x0[1]), (int)bfpack2(x0[2], x0[3]),
                                        (int)bfpack2(x1[0], x1[1]), (int)bfpack2(x1[2], x1[3])};
                        af[mt] = *(bhalf8*)&t;
                    }
                }
                #pragma unroll
                for (int mt = 0; mt < MT; mt++)
                    #pragma unroll
                    for (int j = 0; j < NT; j++)
                        acc[mt][j] = __builtin_amdgcn_mfma_f32_16x16x32_bf16(af[mt], breg[cs][j], acc[mt][j], 0, 0, 0);
            }
        }
    }

    // epilogue: C/D layout col=lane&15, row=quad*4+reg
    float psum[NT], psq[NT];
    #pragma unroll
    for (int j = 0; j < NT; j++) { psum[j] = 0.f; psq[j] = 0.f; }

    #pragma unroll
    for (int j = 0; j < NT; j++) {
        int c = colbase + j * 16 + tl;
        bool cok = c < Nact;
        float bv = (bias && cok) ? bias[c] : 0.f;
        float rsc = 1.f, rsh = 0.f;
        if (res_stats && cok) {
            float mu = res_stats[c] * INV_N;
            float var = res_stats[128 + c] * INV_N - mu * mu;
            rsc = res_g[c] * rsqrtf(var + BN_EPS);
            rsh = res_b[c] - mu * rsc;
        }
        float alc = 0.f, arc = 0.f;
        if constexpr (ELER) { alc = al[c]; arc = ar[c]; }
        #pragma unroll
        for (int mt = 0; mt < MT; mt++) {
            #pragma unroll
            for (int reg = 0; reg < 4; reg++) {
                int r = rowtile + mt * 16 + q * 4 + reg;
                bool rok = r < M;
                float v = 0.f;
                if (rok && cok) {
                    v = acc[mt][j][reg] + bv;
                    if (resv) {
                        size_t ri = (size_t)r * ldres + c;
                        float rv = RESBF ? bf2f(((const unsigned short*)resv)[ri])
                                         : ((const float*)resv)[ri];
                        v = fmaf(rsc, rv, v + rsh);
                    }
                    if (relu) v = fmaxf(v, 0.f);
                    if (out_stats) { psum[j] += v; psq[j] = fmaf(v, v, psq[j]); }
                }
                if constexpr (ELER) {
                    float pel = rsum16(v * alc);
                    float per_ = rsum16(v * arc);
                    if (tl == 0) {
                        int rl = wave * (MT * 16) + mt * 16 + q * 4 + reg;
                        el_s[rl][j] = pel;
                        er_s[rl][j] = per_;
                    }
                }
                if (rok) {
                    if (Cbf) Cbf[(size_t)r * ldc + c] = bf16of(v);
                    else if (cok) C[(size_t)r * ldc + c] = v;
                }
            }
        }
    }

    if constexpr (ELER) {
        __syncthreads();
        int gh = blockIdx.y * NT;
        for (int idx = tid; idx < BROWS * NT; idx += 256) {
            int rl = idx / NT, hj = idx % NT;
            int r = row0b + rl;
            if (r < M) {
                el_out[(size_t)r * 8 + gh + hj] = el_s[rl][hj];
                er_out[(size_t)r * 8 + gh + hj] = er_s[rl][hj];
            }
        }
    }

    if (out_stats) {
        __syncthreads();
        if (tid < 128) { st_sum[tid] = 0.f; st_sq[tid] = 0.f; }
        __syncthreads();
        #pragma unroll
        for (int j = 0; j < NT; j++) {
            int c = colbase + j * 16 + tl;
            if (c < 128) { atomicAdd(&st_sum[c], psum[j]); atomicAdd(&st_sq[c], psq[j]); }
        }
        __syncthreads();
        if (tid < 128) {
            atomicAdd(&out_stats[tid], st_sum[tid]);
            atomicAdd(&out_stats[128 + tid], st_sq[tid]);
        }
    }
}

// ---------------------------------------------------------------- GAT aggregate
// Wave-per-node (R1): one wave covers all 128 dims (lane = 2 dims), iterates all
// edges of its node in-register; stats batched to 1 atomicAdd/thread/block.
__global__ __launch_bounds__(256) void gat_aggregate_kernel(
    const unsigned short* __restrict__ feat,
    const float* __restrict__ el, const float* __restrict__ er,
    const int* __restrict__ indptr, const int* __restrict__ srcs_csr,
    const unsigned short* __restrict__ h_in, int ldh,
    const float* __restrict__ hstats, const float* __restrict__ hg,
    const float* __restrict__ hb,
    const float* __restrict__ bias,
    unsigned short* __restrict__ outp,
    float* __restrict__ stats_rep)
{
    int t = threadIdx.x;
    int w = t >> 6, lane = t & 63;
    int d0 = lane * 2;
    int hh = lane >> 3;
    int pick = lane & 3;
    int gb = lane & 56;
    __shared__ float sred[4][128];
    __shared__ float qred[4][128];

    // hoisted per-dim BN2 affine (for h_in) and gat bias
    float aff_s0 = 1.f, aff_h0 = 0.f, aff_s1 = 1.f, aff_h1 = 0.f;
    if (hstats) {
        float mu0 = hstats[d0] * INV_N;
        float v0  = hstats[128 + d0] * INV_N - mu0 * mu0;
        aff_s0 = hg[d0] * rsqrtf(v0 + BN_EPS);
        aff_h0 = hb[d0] - mu0 * aff_s0;
        float mu1 = hstats[d0 + 1] * INV_N;
        float v1  = hstats[128 + d0 + 1] * INV_N - mu1 * mu1;
        aff_s1 = hg[d0 + 1] * rsqrtf(v1 + BN_EPS);
        aff_h1 = hb[d0 + 1] - mu1 * aff_s1;
    }
    float b0 = bias[d0], b1 = bias[d0 + 1];

    float ss0 = 0.f, sq0 = 0.f, ss1 = 0.f, sq1 = 0.f;
    int nbase = (blockIdx.x * 4 + w) * AGG_NPW;
    #pragma unroll
    for (int ni = 0; ni < AGG_NPW; ni++) {
        int n = nbase + ni;
        if (n >= N_NODES) break;
        int beg = indptr[n], end = indptr[n + 1];
        float ern = er[(size_t)n * 8 + hh];
        float acc0 = 0.f, acc1 = 0.f, den = 0.f;
        int i = beg;
        for (; i + 3 < end; i += 4) {
            int s0 = srcs_csr[i],     s1 = srcs_csr[i + 1];
            int s2 = srcs_csr[i + 2], s3 = srcs_csr[i + 3];
            int sp = pick == 0 ? s0 : pick == 1 ? s1 : pick == 2 ? s2 : s3;
            float ee = el[(size_t)sp * 8 + hh] + ern;
            unsigned f0 = *(const unsigned*)(feat + (size_t)s0 * DIM + d0);
            unsigned f1 = *(const unsigned*)(feat + (size_t)s1 * DIM + d0);
            unsigned f2 = *(const unsigned*)(feat + (size_t)s2 * DIM + d0);
            unsigned f3 = *(const unsigned*)(feat + (size_t)s3 * DIM + d0);
            float aa = expf(ee > 0.f ? ee : NEG_SLOPE * ee);
            float a0 = __shfl(aa, gb + 0);
            float a1 = __shfl(aa, gb + 1);
            float a2 = __shfl(aa, gb + 2);
            float a3 = __shfl(aa, gb + 3);
            den += (a0 + a1) + (a2 + a3);
            acc0 = fmaf(a0, bflo(f0), acc0); acc1 = fmaf(a0, bfhi(f0), acc1);
            acc0 = fmaf(a1, bflo(f1), acc0); acc1 = fmaf(a1, bfhi(f1), acc1);
            acc0 = fmaf(a2, bflo(f2), acc0); acc1 = fmaf(a2, bfhi(f2), acc1);
            acc0 = fmaf(a3, bflo(f3), acc0); acc1 = fmaf(a3, bfhi(f3), acc1);
        }
        for (; i < end; i++) {
            int s0 = srcs_csr[i];
            float e0 = el[(size_t)s0 * 8 + hh] + ern;
            unsigned f0 = *(const unsigned*)(feat + (size_t)s0 * DIM + d0);
            float a0 = expf(e0 > 0.f ? e0 : NEG_SLOPE * e0);
            den += a0;
            acc0 = fmaf(a0, bflo(f0), acc0);
            acc1 = fmaf(a0, bfhi(f0), acc1);
        }
        float inv = den > 0.f ? 1.f / den : 0.f;
        unsigned hu = *(const unsigned*)(h_in + (size_t)n * ldh + d0);
        float hv0 = fmaf(aff_s0, bflo(hu), aff_h0);
        float hv1 = fmaf(aff_s1, bfhi(hu), aff_h1);
        unsigned short u0 = bf16of(hv0 + acc0 * inv + b0);
        unsigned short u1 = bf16of(hv1 + acc1 * inv + b1);
        *(unsigned*)(outp + (size_t)n * DIM + d0) = ((unsigned)u0) | (((unsigned)u1) << 16);
        float vr0 = bf2f(u0), vr1 = bf2f(u1);
        ss0 += vr0; sq0 = fmaf(vr0, vr0, sq0);
        ss1 += vr1; sq1 = fmaf(vr1, vr1, sq1);
    }
    sred[w][d0] = ss0; sred[w][d0 + 1] = ss1;
    qred[w][d0] = sq0; qred[w][d0 + 1] = sq1;
    __syncthreads();
    {
        int d = t & 127;
        float v = (t < 128)
            ? (sred[0][d] + sred[1][d]) + (sred[2][d] + sred[3][d])
            : (qred[0][d] + qred[1][d]) + (qred[2][d] + qred[3][d]);
        float* rep = stats_rep + ((size_t)(blockIdx.x & (NREP - 1)) << 8);
        atomicAdd(&rep[t], v);
    }
}

// ---------------------------------------------------------------- decision head
__global__ __launch_bounds__(256) void decide_kernel(
    const unsigned short* __restrict__ z, const float* __restrict__ stats,
    const float* __restrict__ g, const float* __restrict__ b,
    const float* __restrict__ W2, float* __restrict__ outp, int M)
{
    int wid = threadIdx.x >> 6, lane = threadIdx.x & 63;
    int n = blockIdx.x * 4 + wid;
    if (n >= M) return;
    float acc = 0.f;
    #pragma unroll
    for (int cc = 0; cc < 2; cc++) {
        int c = lane + cc * 64;
        float mu  = stats[c] * INV_N;
        float var = stats[DIM + c] * INV_N - mu * mu;
        float v = fmaf(g[c] * rsqrtf(var + BN_EPS), bf2f(z[(size_t)n * DIM + c]) - mu, b[c]);
        v = fmaxf(v, 0.f);
        acc = fmaf(v, W2[c], acc);
    }
    #pragma unroll
    for (int offs = 32; offs > 0; offs >>= 1)
        acc += __shfl_down(acc, offs);
    if (lane == 0) outp[n] = acc;
}

// ---------------------------------------------------------------- launch
extern "C" void kernel_launch(void* const* d_in, const int* in_sizes, int n_in,
                              void* d_out, int out_size, void* d_ws, size_t ws_size,
                              hipStream_t stream)
{
    const float* x      = (const float*)d_in[0];
    const int*   src    = (const int*)  d_in[1];
    const int*   dst    = (const int*)  d_in[2];
    const float* W_emb  = (const float*)d_in[3];
    const float* b_emb  = (const float*)d_in[4];
    const float* gat_W  = (const float*)d_in[5];
    const float* attn_l = (const float*)d_in[6];
    const float* attn_r = (const float*)d_in[7];
    const float* gat_b  = (const float*)d_in[8];
    const float* bn1_g  = (const float*)d_in[9];
    const float* bn1_b  = (const float*)d_in[10];
    const float* ff_W1  = (const float*)d_in[11];
    const float* ff_b1  = (const float*)d_in[12];
    const float* ff_W2  = (const float*)d_in[13];
    const float* ff_b2  = (const float*)d_in[14];
    const float* bn2_g  = (const float*)d_in[15];
    const float* bn2_b  = (const float*)d_in[16];
    const float* dec_W1 = (const float*)d_in[17];
    const float* dec_bn_g = (const float*)d_in[18];
    const float* dec_bn_b = (const float*)d_in[19];
    const float* dec_W2 = (const float*)d_in[20];
    float* outp = (float*)d_out;

    char* ws = (char*)d_ws;
    size_t off = 0;
    auto alloc = [&](size_t bytes) -> void* {
        void* p = ws + off;
        off += (bytes + 255) & ~(size_t)255;
        return p;
    };
    unsigned short* xsb = (unsigned short*)alloc((size_t)N_NODES * 512 * 2);
    unsigned short* zb  = (unsigned short*)alloc((size_t)N_NODES * DIM * 2);
    unsigned short* featb = (unsigned short*)alloc((size_t)N_NODES * DIM * 2);
    float* el    = (float*)alloc((size_t)N_NODES * HEADS * 4);
    float* er    = (float*)alloc((size_t)N_NODES * HEADS * 4);
    unsigned short* y1b = (unsigned short*)alloc((size_t)N_NODES * 224 * 2);
    unsigned short* btb = (unsigned short*)alloc((size_t)N_NODES * DIM * 2);
    int*   counts= (int*)  alloc((size_t)N_NODES * 4);          // contiguous with statsAll
    float* statsAll = (float*)alloc(((size_t)3 * NREP * 256 + 7 * 256) * 4);
    unsigned short* wpk = (unsigned short*)alloc((size_t)WPK_TOT * 2);
    int*   indptr= (int*)  alloc((size_t)(N_NODES + 1) * 4);
    int*   cursor= (int*)  alloc((size_t)N_NODES * 4);
    int*   srcs_csr = (int*)alloc((size_t)N_EDGES * 4);
    int*   partials = (int*)alloc((size_t)NSEG * 4);
    int*   segoffs  = (int*)alloc((size_t)NSEG * 4);
    (void)ws_size; (void)in_sizes; (void)n_in; (void)out_size;

    float* rep1   = statsAll;                              // + l*NREP*256
    float* stats1c= statsAll + 3 * NREP * 256;             // + l*256
    float* stats2 = statsAll + 3 * NREP * 256 + 3 * 256;   // + l*256
    float* statsD = statsAll + 3 * NREP * 256 + 6 * 256;

    dim3 gg2((N_NODES + 127) / 128, 2);   // layer GEMMs: MT=2, 2 col-groups
    dim3 ggdec((N_NODES + 63) / 64, 2);   // dec: MT=1, NT=4, 2 col-groups, 1250 blocks

    hipMemsetAsync(counts, 0, (size_t)N_NODES * 4 + ((size_t)3 * NREP * 256 + 7 * 256) * 4, stream);
    hist_pack_kernel<<<HIST_BLOCKS + PACK_BLOCKS, 256, 0, stream>>>(
        dst, counts, W_emb, gat_W, ff_W1, ff_W2, dec_W1, wpk);
    // CSR scan: 3-phase reduce-then-scan (measured: replaced 64.7us single-block scan)
    seg_reduce_kernel<<<NSEG, 256, 0, stream>>>(counts, partials);
    seg_offset_kernel<<<1, 64, 0, stream>>>(partials, segoffs, indptr);
    seg_scan_kernel<<<NSEG, 1024, 0, stream>>>(counts, segoffs, indptr, cursor);
    scatter_kernel<<<(N_EDGES + 255) / 256, 256, 0, stream>>>(src, dst, cursor, srcs_csr);

    // embed: xsb[:,0:128] = x @ W_emb + b_emb  (fp32 A, K=64, direct path)
    gemm_l2_kernel<4, 64, 0, false, 2, false, false, false><<<gg2, 256, 0, stream>>>(
        x, nullptr, IN_DIM, wpk + OFF_EMB, b_emb,
        nullptr, 0, nullptr, nullptr, nullptr,
        nullptr, xsb, 512, nullptr,
        N_NODES, DIM, 0, nullptr, nullptr, nullptr, nullptr,
        nullptr, nullptr, nullptr, nullptr);

    for (int l = 0; l < LAYERS; l++) {
        const unsigned short* h_cur = xsb + (size_t)l * DIM;
        const float* hstats = l ? stats2 + (l - 1) * 256 : nullptr;
        const float* hg = l ? bn2_g + (l - 1) * DIM : nullptr;
        const float* hb = l ? bn2_b + (l - 1) * DIM : nullptr;
        // feat = BN2(h) @ gat_W -> bf16, fused el/er  (direct path)
        if (l == 0)
            gemm_l2_kernel<4, 128, 0, true, 2, true, false, false><<<gg2, 256, 0, stream>>>(
                nullptr, h_cur, 512, wpk + OFF_GAT + l * 16384, nullptr,
                nullptr, 0, nullptr, nullptr, nullptr,
                nullptr, featb, DIM, nullptr,
                N_NODES, DIM, 0, nullptr, nullptr, nullptr, nullptr,
                attn_l + l * DIM, attn_r + l * DIM, el, er);
        else
            gemm_l2_kernel<4, 128, 1, true, 2, true, false, false><<<gg2, 256, 0, stream>>>(
                nullptr, h_cur, 512, wpk + OFF_GAT + l * 16384, nullptr,
                nullptr, 0, nullptr, nullptr, nullptr,
                nullptr, featb, DIM, nullptr,
                N_NODES, DIM, 0, hstats, nullptr, hg, hb,
                attn_l + l * DIM, attn_r + l * DIM, el, er);
        // btb = BN2(h) + agg + bias  (pre-BN1, bf16); inline edge exp; fused BN1 rep-stats
        gat_aggregate_kernel<<<AGG_BLOCKS, 256, 0, stream>>>(
            featb, el, er, indptr, srcs_csr, h_cur, 512,
            hstats, hg, hb, gat_b + l * DIM, btb,
            rep1 + (size_t)l * NREP * 256);
        // FFN1: y1 = relu(BN1(btb) @ W1 + b1) -> bf16 ld224; AMODE=3 sums replicas (direct)
        gemm_l2_kernel<7, 128, 3, true, 2, false, false, false><<<gg2, 256, 0, stream>>>(
            nullptr, btb, DIM, wpk + OFF_W1 + l * 28672,
            ff_b1 + l * FF_DIM,
            nullptr, 0, nullptr, nullptr, nullptr,
            nullptr, y1b, 224, nullptr,
            N_NODES, FF_DIM, 1,
            rep1 + (size_t)l * NREP * 256, stats1c + l * 256,
            bn1_g + l * DIM, bn1_b + l * DIM,
            nullptr, nullptr, nullptr, nullptr);
        // FFN2: t = y1 @ W2 + b2 + BN1(btb) -> xsb block l+1 (bf16) + bn2 stats (direct)
        gemm_l2_kernel<4, 224, 0, true, 2, false, true, false><<<gg2, 256, 0, stream>>>(
            nullptr, y1b, 224, wpk + OFF_W2 + l * 28672,
            ff_b2 + l * DIM,
            btb, DIM, stats1c + l * 256, bn1_g + l * DIM, bn1_b + l * DIM,
            nullptr, xsb + (size_t)(l + 1) * DIM, 512, stats2 + l * 256,
            N_NODES, DIM, 0, nullptr, nullptr, nullptr, nullptr,
            nullptr, nullptr, nullptr, nullptr);
    }

    // dec: z = BN-affine-concat(xsb) @ dec_W1 (bf16 out) + dec stats
    // (MT=1, NT=4, 2 col-groups, chunked LDS-B + 8-deep A-ring)
    gemm_l2_kernel<4, 512, 2, true, 1, false, false, true><<<ggdec, 256, 0, stream>>>(
        nullptr, xsb, 512, wpk + OFF_DEC, nullptr,
        nullptr, 0, nullptr, nullptr, nullptr,
        nullptr, zb, DIM, statsD,
        N_NODES, DIM, 0, stats2, nullptr, bn2_g, bn2_b,
        nullptr, nullptr, nullptr, nullptr);
    decide_kernel<<<(N_NODES + 3) / 4, 256, 0, stream>>>(
        zb, statsD, dec_bn_g, dec_bn_b, dec_W2, outp, N_NODES);
}

// Round 24
// 644.254 us; speedup vs baseline: 1.0159x; 1.0159x over previous
//
#include <hip/hip_runtime.h>
#include <hip/hip_bf16.h>
#include <math.h>

#define N_NODES 40000
#define N_EDGES 640000
#define DIM     128
#define HEADS   8
#define DHEAD   16
#define LAYERS  3
#define IN_DIM  64
#define FF_DIM  218
#define BN_EPS  1e-5f
#define NEG_SLOPE 0.2f
#define INV_N   (1.f / N_NODES)
#define NREP    128
#define AGG_NPW 2                      // nodes per wave in aggregate
#define AGG_BLOCKS (N_NODES / (4 * AGG_NPW))   // 5000
#define SEG     1000                   // CSR scan segment
#define NSEG    40                     // N_NODES / SEG

typedef __attribute__((ext_vector_type(8))) short  bhalf8;
typedef __attribute__((ext_vector_type(4))) float  floatx4;
typedef __attribute__((ext_vector_type(4))) int    intx4;

__device__ __forceinline__ unsigned bfpack2(float a, float b) {
    unsigned ua = __float_as_uint(a);
    ua = ua + 0x7FFFu + ((ua >> 16) & 1u);
    unsigned ub = __float_as_uint(b);
    ub = ub + 0x7FFFu + ((ub >> 16) & 1u);
    return (ua >> 16) | (ub & 0xFFFF0000u);
}
__device__ __forceinline__ unsigned short bf16of(float a) {
    unsigned ua = __float_as_uint(a);
    ua = ua + 0x7FFFu + ((ua >> 16) & 1u);
    return (unsigned short)(ua >> 16);
}
__device__ __forceinline__ float bf2f(unsigned short u) {
    return __uint_as_float(((unsigned)u) << 16);
}
__device__ __forceinline__ float bflo(unsigned u) { return __uint_as_float(u << 16); }
__device__ __forceinline__ float bfhi(unsigned u) { return __uint_as_float(u & 0xFFFF0000u); }
__device__ __forceinline__ float rsum16(float v) {
    v += __shfl_xor(v, 1, 16);
    v += __shfl_xor(v, 2, 16);
    v += __shfl_xor(v, 4, 16);
    v += __shfl_xor(v, 8, 16);
    return v;
}

// packed weight layout offsets (bf16 elements)
#define OFF_EMB 0
#define OFF_GAT 8192
#define OFF_W1  57344
#define OFF_W2  143360
#define OFF_DEC 229376
#define WPK_TOT 294912
#define HIST_BLOCKS ((N_EDGES + 255) / 256)
#define PACK_BLOCKS ((WPK_TOT + 255) / 256)

// ---------------------------------------------------------------- hist + weight pre-pack (merged)
__global__ void hist_pack_kernel(const int* __restrict__ dst, int* __restrict__ counts,
                                 const float* __restrict__ W_emb,
                                 const float* __restrict__ gat_W,
                                 const float* __restrict__ ff_W1,
                                 const float* __restrict__ ff_W2,
                                 const float* __restrict__ dec_W1,
                                 unsigned short* __restrict__ wpk) {
    int bid = blockIdx.x;
    if (bid < HIST_BLOCKS) {
        int e = bid * 256 + threadIdx.x;
        if (e < N_EDGES) atomicAdd(&counts[dst[e]], 1);
        return;
    }
    int i = (bid - HIST_BLOCKS) * 256 + threadIdx.x;
    if (i >= WPK_TOT) return;
    int o = i;
    if (o < 8192) {                       // emb: [128][64]
        int n = o >> 6, k = o & 63;
        wpk[OFF_EMB + o] = bf16of(W_emb[k * 128 + n]);
        return;
    }
    o -= 8192;
    if (o < 3 * 16384) {                  // gat: [l][128][128]
        int l = o >> 14, r = o & 16383;
        int n = r >> 7, k = r & 127;
        wpk[OFF_GAT + o] = bf16of(gat_W[l * 16384 + k * 128 + n]);
        return;
    }
    o -= 3 * 16384;
    if (o < 3 * 28672) {                  // W1: [l][224][128]
        int l = o / 28672, r = o % 28672;
        int n = r >> 7, k = r & 127;
        float v = (n < FF_DIM) ? ff_W1[(size_t)l * 128 * FF_DIM + k * FF_DIM + n] : 0.f;
        wpk[OFF_W1 + o] = bf16of(v);
        return;
    }
    o -= 3 * 28672;
    if (o < 3 * 28672) {                  // W2: [l][128][224]
        int l = o / 28672, r = o % 28672;
        int n = r / 224, k = r % 224;
        float v = (k < FF_DIM) ? ff_W2[(size_t)l * FF_DIM * 128 + k * 128 + n] : 0.f;
        wpk[OFF_W2 + o] = bf16of(v);
        return;
    }
    o -= 3 * 28672;
    {                                     // dec: [128][512]
        int n = o >> 9, k = o & 511;
        wpk[OFF_DEC + o] = bf16of(dec_W1[k * 128 + n]);
    }
}

// ---------------------------------------------------------------- CSR build (R14, measured -49us)
// 3-phase reduce-then-scan replaced the 64.7us single-block scan (0.13% occ).
__global__ void seg_reduce_kernel(const int* __restrict__ counts, int* __restrict__ partials) {
    __shared__ int wsum[4];
    int b = blockIdx.x, tid = threadIdx.x;
    int s = 0;
    for (int i = tid; i < SEG; i += 256) {
        int idx = b * SEG + i;
        if (idx < N_NODES) s += counts[idx];
    }
    #pragma unroll
    for (int o = 32; o > 0; o >>= 1) s += __shfl_down(s, o);
    if ((tid & 63) == 0) wsum[tid >> 6] = s;
    __syncthreads();
    if (tid == 0) partials[b] = (wsum[0] + wsum[1]) + (wsum[2] + wsum[3]);
}

__global__ void seg_offset_kernel(const int* __restrict__ partials, int* __restrict__ offs,
                                  int* __restrict__ indptr) {
    int lane = threadIdx.x;
    int p = (lane < NSEG) ? partials[lane] : 0;
    int v = p;
    #pragma unroll
    for (int d = 1; d < 64; d <<= 1) {
        int t = __shfl_up(v, d);
        if (lane >= d) v += t;
    }
    if (lane < NSEG) offs[lane] = v - p;         // exclusive
    if (lane == NSEG - 1) indptr[N_NODES] = v;   // grand total
}

__global__ __launch_bounds__(1024) void seg_scan_kernel(const int* __restrict__ counts,
                                                        const int* __restrict__ offs,
                                                        int* __restrict__ indptr,
                                                        int* __restrict__ cursor) {
    __shared__ int tsum[1024];
    int b = blockIdx.x, tid = threadIdx.x;
    int idx = b * SEG + tid;
    int v = (tid < SEG && idx < N_NODES) ? counts[idx] : 0;
    tsum[tid] = v;
    __syncthreads();
    for (int o = 1; o < 1024; o <<= 1) {
        int t = (tid >= o) ? tsum[tid - o] : 0;
        __syncthreads();
        tsum[tid] += t;
        __syncthreads();
    }
    if (tid < SEG && idx < N_NODES) {
        int e = offs[b] + tsum[tid] - v;   // exclusive + segment offset
        indptr[idx] = e;
        cursor[idx] = e;
    }
}

__global__ void scatter_kernel(const int* __restrict__ src, const int* __restrict__ dst,
                               int* __restrict__ cursor,
                               int* __restrict__ srcs_csr) {
    int e = blockIdx.x * blockDim.x + threadIdx.x;
    if (e < N_EDGES) {
        int d = dst[e];
        int pos = atomicAdd(&cursor[d], 1);
        srcs_csr[pos] = src[e];
    }
}

// ---------------------------------------------------------------- L2-resident-B GEMM
// R22 post-mortem: PD 4->8 NEUTRAL (654.5 vs 651.9; dec pinned at 61us/875GB/s)
// -> per-wave in-flight depth is NOT the limiter; wave-level TLP already covers
// it (m114-style). Pre-registered alternative fires: occupancy is LDS-capped
// (38.9KB -> 4 blocks/CU). R23: KCH 256->128 for dec — Bs=17.4KB (~22.6KB
// total) -> 7 blocks/CU, ~2x resident waves. 4 chunks instead of 2 (stage is
// L2-hot, cheap); PD collapses to 4 via min (proven equivalent to 8).
// Only dec has KPAD>256; all other dispatches byte-identical.
// AMODE: 0 none; 1 BN affine on A; 2 dec512 layered affine; 3 NREP-replica stats.
template<int NT, int KPAD, int AMODE, bool ABF16, int MT, bool ELER, bool RESBF, bool BLDS>
__global__ __launch_bounds__(256) void gemm_l2_kernel(
    const float* __restrict__ A, const unsigned short* __restrict__ Abf, int lda,
    const unsigned short* __restrict__ Bpk,
    const float* __restrict__ bias,
    const void* __restrict__ resv, int ldres,
    const float* __restrict__ res_stats, const float* __restrict__ res_g,
    const float* __restrict__ res_b,
    float* __restrict__ C, unsigned short* __restrict__ Cbf, int ldc,
    float* __restrict__ out_stats,
    int M, int Nact, int relu,
    const float* __restrict__ a_stats, float* __restrict__ a_stats_out,
    const float* __restrict__ a_g, const float* __restrict__ a_b,
    const float* __restrict__ al, const float* __restrict__ ar,
    float* __restrict__ el_out, float* __restrict__ er_out)
{
    constexpr int SCN = (AMODE > 0) ? KPAD : 1;
    constexpr int BROWS = 64 * MT;
    constexpr int STEPS = KPAD / 32;
    constexpr int KCH = (KPAD > 256) ? 128 : KPAD;   // B-stage chunk (R23: 256->128)
    constexpr int BPKC = KCH + 8;                    // padded LDS row (odd 16B-slot stride)
    __shared__ float sc_s[SCN];
    __shared__ float sh_s[SCN];
    __shared__ float st_sum[128];
    __shared__ float st_sq[128];
    __shared__ float el_s[ELER ? BROWS : 1][ELER ? NT : 1];
    __shared__ float er_s[ELER ? BROWS : 1][ELER ? NT : 1];
    __shared__ unsigned short Bs[(BLDS && ABF16) ? NT * 16 * BPKC : 1];

    int tid = threadIdx.x, wave = tid >> 6, lane = tid & 63;
    int q = lane >> 4, tl = lane & 15;
    int colbase = blockIdx.y * (NT * 16);
    int row0b = blockIdx.x * BROWS;
    int rowtile = row0b + wave * (MT * 16);

    if constexpr (AMODE == 1 || AMODE == 2) {
        for (int idx = tid; idx < KPAD; idx += 256) {
            float scv = 1.f, shv = 0.f;
            if constexpr (AMODE == 1) {
                float mu = a_stats[idx] * INV_N;
                float var = a_stats[128 + idx] * INV_N - mu * mu;
                scv = a_g[idx] * rsqrtf(var + BN_EPS);
                shv = a_b[idx] - mu * scv;
            } else {
                int l = idx >> 7;
                if (l > 0) {
                    int c = idx & 127;
                    const float* st = a_stats + (l - 1) * 256;
                    float mu = st[c] * INV_N;
                    float var = st[128 + c] * INV_N - mu * mu;
                    scv = a_g[(l - 1) * 128 + c] * rsqrtf(var + BN_EPS);
                    shv = a_b[(l - 1) * 128 + c] - mu * scv;
                }
            }
            sc_s[idx] = scv;
            sh_s[idx] = shv;
        }
        __syncthreads();
    }
    if constexpr (AMODE == 3) {
        for (int idx = tid; idx < 128; idx += 256) {
            float s = 0.f, sq = 0.f;
            #pragma unroll 8
            for (int r = 0; r < NREP; r++) {
                s  += a_stats[r * 256 + idx];
                sq += a_stats[r * 256 + 128 + idx];
            }
            a_stats_out[idx] = s;            // benign identical-value race
            a_stats_out[128 + idx] = sq;
            float mu = s * INV_N;
            float var = sq * INV_N - mu * mu;
            float scv = a_g[idx] * rsqrtf(var + BN_EPS);
            sc_s[idx] = scv;
            sh_s[idx] = a_b[idx] - mu * scv;
        }
        __syncthreads();
    }

    int rowm[MT];
    bool vrm[MT];
    #pragma unroll
    for (int mt = 0; mt < MT; mt++) {
        rowm[mt] = rowtile + mt * 16 + tl;
        vrm[mt] = rowm[mt] < M;
    }
    const unsigned short* bp = Bpk + (size_t)colbase * KPAD;

    floatx4 acc[MT][NT] = {};

    if constexpr (BLDS && ABF16) {
        constexpr int NCH = KPAD / KCH;
        constexpr int CSTEPS = KCH / 32;
        constexpr int PD = (CSTEPS >= 8) ? 8 : CSTEPS;
        for (int ch = 0; ch < NCH; ch++) {
            const int kbase = ch * KCH;
            // stage this K-chunk of the B panel -> LDS (coalesced 16B/lane)
            for (int idx = tid; idx < NT * 16 * (KCH / 8); idx += 256) {
                int col = idx / (KCH / 8), k8 = idx % (KCH / 8);
                *(intx4*)(Bs + col * BPKC + k8 * 8) =
                    *(const intx4*)(bp + (size_t)col * KPAD + kbase + k8 * 8);
            }
            __syncthreads();
            // A-ring: PD-1 steps in flight; B via ds_read (independent lgkmcnt)
            intx4 ap[PD][MT];
            #pragma unroll
            for (int s = 0; s < PD - 1; s++) {
                int gk = kbase + s * 32 + q * 8;
                #pragma unroll
                for (int mt = 0; mt < MT; mt++) {
                    intx4 u = {};
                    if (vrm[mt]) u = *(const intx4*)(Abf + (size_t)rowm[mt] * lda + gk);
                    ap[s][mt] = u;
                }
            }
            #pragma unroll
            for (int s = 0; s < CSTEPS; s++) {
                int lk = s * 32 + q * 8;
                int gk = kbase + lk;
                if (s + PD - 1 < CSTEPS) {
                    int gk2 = kbase + (s + PD - 1) * 32 + q * 8;
                    #pragma unroll
                    for (int mt = 0; mt < MT; mt++) {
                        intx4 u = {};
                        if (vrm[mt]) u = *(const intx4*)(Abf + (size_t)rowm[mt] * lda + gk2);
                        ap[(s + PD - 1) % PD][mt] = u;
                    }
                }
                bhalf8 breg[NT];
                #pragma unroll
                for (int j = 0; j < NT; j++)
                    breg[j] = *(const bhalf8*)(Bs + (j * 16 + tl) * BPKC + lk);
                bhalf8 af[MT];
                #pragma unroll
                for (int mt = 0; mt < MT; mt++) {
                    intx4 u = ap[s % PD][mt];
                    if constexpr (AMODE > 0) {
                        #pragma unroll
                        for (int w = 0; w < 4; w++) {
                            unsigned uw = (unsigned)u[w];
                            float lo = bflo(uw), hi = bfhi(uw);
                            lo = fmaf(sc_s[gk + 2 * w],     lo, sh_s[gk + 2 * w]);
                            hi = fmaf(sc_s[gk + 2 * w + 1], hi, sh_s[gk + 2 * w + 1]);
                            u[w] = (int)bfpack2(lo, hi);
                        }
                    }
                    af[mt] = *(bhalf8*)&u;
                }
                #pragma unroll
                for (int mt = 0; mt < MT; mt++)
                    #pragma unroll
                    for (int j = 0; j < NT; j++)
                        acc[mt][j] = __builtin_amdgcn_mfma_f32_16x16x32_bf16(af[mt], breg[j], acc[mt][j], 0, 0, 0);
            }
            __syncthreads();   // protect Bs before next chunk's restage
        }
    } else {
        // R5 direct path (measured-best for short K): CST=2 grouped loads
        constexpr int CST = (STEPS > 2) ? 2 : STEPS;
        #pragma unroll
        for (int c0 = 0; c0 < STEPS; c0 += CST) {
            intx4  arawb[CST][MT];
            floatx4 araw0[ABF16 ? 1 : CST][ABF16 ? 1 : MT];
            floatx4 araw1[ABF16 ? 1 : CST][ABF16 ? 1 : MT];
            bhalf8 breg[CST][NT];
            #pragma unroll
            for (int cs = 0; cs < CST; cs++) {
                if (c0 + cs >= STEPS) continue;
                int gk = (c0 + cs) * 32 + q * 8;
                #pragma unroll
                for (int j = 0; j < NT; j++)
                    breg[cs][j] = *(const bhalf8*)(bp + (size_t)(j * 16 + tl) * KPAD + gk);
                #pragma unroll
                for (int mt = 0; mt < MT; mt++) {
                    if constexpr (ABF16) {
                        intx4 u = {};
                        if (vrm[mt]) u = *(const intx4*)(Abf + (size_t)rowm[mt] * lda + gk);
                        arawb[cs][mt] = u;
                    } else {
                        floatx4 x0 = {}, x1 = {};
                        if (vrm[mt]) {
                            const float* apt = A + (size_t)rowm[mt] * lda + gk;
                            x0 = *(const floatx4*)apt;
                            x1 = *(const floatx4*)(apt + 4);
                        }
                        araw0[cs][mt] = x0;
                        araw1[cs][mt] = x1;
                    }
                }
            }
            #pragma unroll
            for (int cs = 0; cs < CST; cs++) {
                if (c0 + cs >= STEPS) continue;
                int gk = (c0 + cs) * 32 + q * 8;
                bhalf8 af[MT];
                #pragma unroll
                for (int mt = 0; mt < MT; mt++) {
                    if constexpr (ABF16) {
                        intx4 u = arawb[cs][mt];
                        if constexpr (AMODE > 0) {
                            #pragma unroll
                            for (int w = 0; w < 4; w++) {
                                unsigned uw = (unsigned)u[w];
                                float lo = bflo(uw), hi = bfhi(uw);
                                lo = fmaf(sc_s[gk + 2 * w],     lo, sh_s[gk + 2 * w]);
                                hi = fmaf(sc_s[gk + 2 * w + 1], hi, sh_s[gk + 2 * w + 1]);
                                u[w] = (int)bfpack2(lo, hi);
                            }
                        }
                        af[mt] = *(bhalf8*)&u;
                    } else {
                        floatx4 x0 = araw0[cs][mt], x1 = araw1[cs][mt];
                        if constexpr (AMODE > 0) {
                            #pragma unroll
                            for (int jj = 0; jj < 4; jj++) {
                                x0[jj] = fmaf(sc_s[gk + jj],     x0[jj], sh_s[gk + jj]);
                                x1[jj] = fmaf(sc_s[gk + 4 + jj], x1[jj], sh_s[gk + 4 + jj]);
                            }
                        }
                        intx4 t = intx4{(int)bfpack2(x0[0], x0[1]), (int)bfpack2(x0[2], x0[3]),
                                        (int)bfpack2(x1[0], x1[1]), (int)bfpack2(x1[2], x1[3])};
                        af[mt] = *(bhalf8*)&t;
                    }
                }
                #pragma unroll
                for (int mt = 0; mt < MT; mt++)
                    #pragma unroll
                    for (int j = 0; j < NT; j++)
                        acc[mt][j] = __builtin_amdgcn_mfma_f32_16x16x32_bf16(af[mt], breg[cs][j], acc[mt][j], 0, 0, 0);
            }
        }
    }

    // epilogue: C/D layout col=lane&15, row=quad*4+reg
    float psum[NT], psq[NT];
    #pragma unroll
    for (int j = 0; j < NT; j++) { psum[j] = 0.f; psq[j] = 0.f; }

    #pragma unroll
    for (int j = 0; j < NT; j++) {
        int c = colbase + j * 16 + tl;
        bool cok = c < Nact;
        float bv = (bias && cok) ? bias[c] : 0.f;
        float rsc = 1.f, rsh = 0.f;
        if (res_stats && cok) {
            float mu = res_stats[c] * INV_N;
            float var = res_stats[128 + c] * INV_N - mu * mu;
            rsc = res_g[c] * rsqrtf(var + BN_EPS);
            rsh = res_b[c] - mu * rsc;
        }
        float alc = 0.f, arc = 0.f;
        if constexpr (ELER) { alc = al[c]; arc = ar[c]; }
        #pragma unroll
        for (int mt = 0; mt < MT; mt++) {
            #pragma unroll
            for (int reg = 0; reg < 4; reg++) {
                int r = rowtile + mt * 16 + q * 4 + reg;
                bool rok = r < M;
                float v = 0.f;
                if (rok && cok) {
                    v = acc[mt][j][reg] + bv;
                    if (resv) {
                        size_t ri = (size_t)r * ldres + c;
                        float rv = RESBF ? bf2f(((const unsigned short*)resv)[ri])
                                         : ((const float*)resv)[ri];
                        v = fmaf(rsc, rv, v + rsh);
                    }
                    if (relu) v = fmaxf(v, 0.f);
                    if (out_stats) { psum[j] += v; psq[j] = fmaf(v, v, psq[j]); }
                }
                if constexpr (ELER) {
                    float pel = rsum16(v * alc);
                    float per_ = rsum16(v * arc);
                    if (tl == 0) {
                        int rl = wave * (MT * 16) + mt * 16 + q * 4 + reg;
                        el_s[rl][j] = pel;
                        er_s[rl][j] = per_;
                    }
                }
                if (rok) {
                    if (Cbf) Cbf[(size_t)r * ldc + c] = bf16of(v);
                    else if (cok) C[(size_t)r * ldc + c] = v;
                }
            }
        }
    }

    if constexpr (ELER) {
        __syncthreads();
        int gh = blockIdx.y * NT;
        for (int idx = tid; idx < BROWS * NT; idx += 256) {
            int rl = idx / NT, hj = idx % NT;
            int r = row0b + rl;
            if (r < M) {
                el_out[(size_t)r * 8 + gh + hj] = el_s[rl][hj];
                er_out[(size_t)r * 8 + gh + hj] = er_s[rl][hj];
            }
        }
    }

    if (out_stats) {
        __syncthreads();
        if (tid < 128) { st_sum[tid] = 0.f; st_sq[tid] = 0.f; }
        __syncthreads();
        #pragma unroll
        for (int j = 0; j < NT; j++) {
            int c = colbase + j * 16 + tl;
            if (c < 128) { atomicAdd(&st_sum[c], psum[j]); atomicAdd(&st_sq[c], psq[j]); }
        }
        __syncthreads();
        if (tid < 128) {
            atomicAdd(&out_stats[tid], st_sum[tid]);
            atomicAdd(&out_stats[128 + tid], st_sq[tid]);
        }
    }
}

// ---------------------------------------------------------------- GAT aggregate
// Wave-per-node (R1): one wave covers all 128 dims (lane = 2 dims), iterates all
// edges of its node in-register; stats batched to 1 atomicAdd/thread/block.
__global__ __launch_bounds__(256) void gat_aggregate_kernel(
    const unsigned short* __restrict__ feat,
    const float* __restrict__ el, const float* __restrict__ er,
    const int* __restrict__ indptr, const int* __restrict__ srcs_csr,
    const unsigned short* __restrict__ h_in, int ldh,
    const float* __restrict__ hstats, const float* __restrict__ hg,
    const float* __restrict__ hb,
    const float* __restrict__ bias,
    unsigned short* __restrict__ outp,
    float* __restrict__ stats_rep)
{
    int t = threadIdx.x;
    int w = t >> 6, lane = t & 63;
    int d0 = lane * 2;
    int hh = lane >> 3;
    int pick = lane & 3;
    int gb = lane & 56;
    __shared__ float sred[4][128];
    __shared__ float qred[4][128];

    // hoisted per-dim BN2 affine (for h_in) and gat bias
    float aff_s0 = 1.f, aff_h0 = 0.f, aff_s1 = 1.f, aff_h1 = 0.f;
    if (hstats) {
        float mu0 = hstats[d0] * INV_N;
        float v0  = hstats[128 + d0] * INV_N - mu0 * mu0;
        aff_s0 = hg[d0] * rsqrtf(v0 + BN_EPS);
        aff_h0 = hb[d0] - mu0 * aff_s0;
        float mu1 = hstats[d0 + 1] * INV_N;
        float v1  = hstats[128 + d0 + 1] * INV_N - mu1 * mu1;
        aff_s1 = hg[d0 + 1] * rsqrtf(v1 + BN_EPS);
        aff_h1 = hb[d0 + 1] - mu1 * aff_s1;
    }
    float b0 = bias[d0], b1 = bias[d0 + 1];

    float ss0 = 0.f, sq0 = 0.f, ss1 = 0.f, sq1 = 0.f;
    int nbase = (blockIdx.x * 4 + w) * AGG_NPW;
    #pragma unroll
    for (int ni = 0; ni < AGG_NPW; ni++) {
        int n = nbase + ni;
        if (n >= N_NODES) break;
        int beg = indptr[n], end = indptr[n + 1];
        float ern = er[(size_t)n * 8 + hh];
        float acc0 = 0.f, acc1 = 0.f, den = 0.f;
        int i = beg;
        for (; i + 3 < end; i += 4) {
            int s0 = srcs_csr[i],     s1 = srcs_csr[i + 1];
            int s2 = srcs_csr[i + 2], s3 = srcs_csr[i + 3];
            int sp = pick == 0 ? s0 : pick == 1 ? s1 : pick == 2 ? s2 : s3;
            float ee = el[(size_t)sp * 8 + hh] + ern;
            unsigned f0 = *(const unsigned*)(feat + (size_t)s0 * DIM + d0);
            unsigned f1 = *(const unsigned*)(feat + (size_t)s1 * DIM + d0);
            unsigned f2 = *(const unsigned*)(feat + (size_t)s2 * DIM + d0);
            unsigned f3 = *(const unsigned*)(feat + (size_t)s3 * DIM + d0);
            float aa = expf(ee > 0.f ? ee : NEG_SLOPE * ee);
            float a0 = __shfl(aa, gb + 0);
            float a1 = __shfl(aa, gb + 1);
            float a2 = __shfl(aa, gb + 2);
            float a3 = __shfl(aa, gb + 3);
            den += (a0 + a1) + (a2 + a3);
            acc0 = fmaf(a0, bflo(f0), acc0); acc1 = fmaf(a0, bfhi(f0), acc1);
            acc0 = fmaf(a1, bflo(f1), acc0); acc1 = fmaf(a1, bfhi(f1), acc1);
            acc0 = fmaf(a2, bflo(f2), acc0); acc1 = fmaf(a2, bfhi(f2), acc1);
            acc0 = fmaf(a3, bflo(f3), acc0); acc1 = fmaf(a3, bfhi(f3), acc1);
        }
        for (; i < end; i++) {
            int s0 = srcs_csr[i];
            float e0 = el[(size_t)s0 * 8 + hh] + ern;
            unsigned f0 = *(const unsigned*)(feat + (size_t)s0 * DIM + d0);
            float a0 = expf(e0 > 0.f ? e0 : NEG_SLOPE * e0);
            den += a0;
            acc0 = fmaf(a0, bflo(f0), acc0);
            acc1 = fmaf(a0, bfhi(f0), acc1);
        }
        float inv = den > 0.f ? 1.f / den : 0.f;
        unsigned hu = *(const unsigned*)(h_in + (size_t)n * ldh + d0);
        float hv0 = fmaf(aff_s0, bflo(hu), aff_h0);
        float hv1 = fmaf(aff_s1, bfhi(hu), aff_h1);
        unsigned short u0 = bf16of(hv0 + acc0 * inv + b0);
        unsigned short u1 = bf16of(hv1 + acc1 * inv + b1);
        *(unsigned*)(outp + (size_t)n * DIM + d0) = ((unsigned)u0) | (((unsigned)u1) << 16);
        float vr0 = bf2f(u0), vr1 = bf2f(u1);
        ss0 += vr0; sq0 = fmaf(vr0, vr0, sq0);
        ss1 += vr1; sq1 = fmaf(vr1, vr1, sq1);
    }
    sred[w][d0] = ss0; sred[w][d0 + 1] = ss1;
    qred[w][d0] = sq0; qred[w][d0 + 1] = sq1;
    __syncthreads();
    {
        int d = t & 127;
        float v = (t < 128)
            ? (sred[0][d] + sred[1][d]) + (sred[2][d] + sred[3][d])
            : (qred[0][d] + qred[1][d]) + (qred[2][d] + qred[3][d]);
        float* rep = stats_rep + ((size_t)(blockIdx.x & (NREP - 1)) << 8);
        atomicAdd(&rep[t], v);
    }
}

// ---------------------------------------------------------------- decision head
__global__ __launch_bounds__(256) void decide_kernel(
    const unsigned short* __restrict__ z, const float* __restrict__ stats,
    const float* __restrict__ g, const float* __restrict__ b,
    const float* __restrict__ W2, float* __restrict__ outp, int M)
{
    int wid = threadIdx.x >> 6, lane = threadIdx.x & 63;
    int n = blockIdx.x * 4 + wid;
    if (n >= M) return;
    float acc = 0.f;
    #pragma unroll
    for (int cc = 0; cc < 2; cc++) {
        int c = lane + cc * 64;
        float mu  = stats[c] * INV_N;
        float var = stats[DIM + c] * INV_N - mu * mu;
        float v = fmaf(g[c] * rsqrtf(var + BN_EPS), bf2f(z[(size_t)n * DIM + c]) - mu, b[c]);
        v = fmaxf(v, 0.f);
        acc = fmaf(v, W2[c], acc);
    }
    #pragma unroll
    for (int offs = 32; offs > 0; offs >>= 1)
        acc += __shfl_down(acc, offs);
    if (lane == 0) outp[n] = acc;
}

// ---------------------------------------------------------------- launch
extern "C" void kernel_launch(void* const* d_in, const int* in_sizes, int n_in,
                              void* d_out, int out_size, void* d_ws, size_t ws_size,
                              hipStream_t stream)
{
    const float* x      = (const float*)d_in[0];
    const int*   src    = (const int*)  d_in[1];
    const int*   dst    = (const int*)  d_in[2];
    const float* W_emb  = (const float*)d_in[3];
    const float* b_emb  = (const float*)d_in[4];
    const float* gat_W  = (const float*)d_in[5];
    const float* attn_l = (const float*)d_in[6];
    const float* attn_r = (const float*)d_in[7];
    const float* gat_b  = (const float*)d_in[8];
    const float* bn1_g  = (const float*)d_in[9];
    const float* bn1_b  = (const float*)d_in[10];
    const float* ff_W1  = (const float*)d_in[11];
    const float* ff_b1  = (const float*)d_in[12];
    const float* ff_W2  = (const float*)d_in[13];
    const float* ff_b2  = (const float*)d_in[14];
    const float* bn2_g  = (const float*)d_in[15];
    const float* bn2_b  = (const float*)d_in[16];
    const float* dec_W1 = (const float*)d_in[17];
    const float* dec_bn_g = (const float*)d_in[18];
    const float* dec_bn_b = (const float*)d_in[19];
    const float* dec_W2 = (const float*)d_in[20];
    float* outp = (float*)d_out;

    char* ws = (char*)d_ws;
    size_t off = 0;
    auto alloc = [&](size_t bytes) -> void* {
        void* p = ws + off;
        off += (bytes + 255) & ~(size_t)255;
        return p;
    };
    unsigned short* xsb = (unsigned short*)alloc((size_t)N_NODES * 512 * 2);
    unsigned short* zb  = (unsigned short*)alloc((size_t)N_NODES * DIM * 2);
    unsigned short* featb = (unsigned short*)alloc((size_t)N_NODES * DIM * 2);
    float* el    = (float*)alloc((size_t)N_NODES * HEADS * 4);
    float* er    = (float*)alloc((size_t)N_NODES * HEADS * 4);
    unsigned short* y1b = (unsigned short*)alloc((size_t)N_NODES * 224 * 2);
    unsigned short* btb = (unsigned short*)alloc((size_t)N_NODES * DIM * 2);
    int*   counts= (int*)  alloc((size_t)N_NODES * 4);          // contiguous with statsAll
    float* statsAll = (float*)alloc(((size_t)3 * NREP * 256 + 7 * 256) * 4);
    unsigned short* wpk = (unsigned short*)alloc((size_t)WPK_TOT * 2);
    int*   indptr= (int*)  alloc((size_t)(N_NODES + 1) * 4);
    int*   cursor= (int*)  alloc((size_t)N_NODES * 4);
    int*   srcs_csr = (int*)alloc((size_t)N_EDGES * 4);
    int*   partials = (int*)alloc((size_t)NSEG * 4);
    int*   segoffs  = (int*)alloc((size_t)NSEG * 4);
    (void)ws_size; (void)in_sizes; (void)n_in; (void)out_size;

    float* rep1   = statsAll;                              // + l*NREP*256
    float* stats1c= statsAll + 3 * NREP * 256;             // + l*256
    float* stats2 = statsAll + 3 * NREP * 256 + 3 * 256;   // + l*256
    float* statsD = statsAll + 3 * NREP * 256 + 6 * 256;

    dim3 gg2((N_NODES + 127) / 128, 2);   // layer GEMMs: MT=2, 2 col-groups
    dim3 ggdec((N_NODES + 63) / 64, 2);   // dec: MT=1, NT=4, 2 col-groups, 1250 blocks

    hipMemsetAsync(counts, 0, (size_t)N_NODES * 4 + ((size_t)3 * NREP * 256 + 7 * 256) * 4, stream);
    hist_pack_kernel<<<HIST_BLOCKS + PACK_BLOCKS, 256, 0, stream>>>(
        dst, counts, W_emb, gat_W, ff_W1, ff_W2, dec_W1, wpk);
    // CSR scan: 3-phase reduce-then-scan (measured: replaced 64.7us single-block scan)
    seg_reduce_kernel<<<NSEG, 256, 0, stream>>>(counts, partials);
    seg_offset_kernel<<<1, 64, 0, stream>>>(partials, segoffs, indptr);
    seg_scan_kernel<<<NSEG, 1024, 0, stream>>>(counts, segoffs, indptr, cursor);
    scatter_kernel<<<(N_EDGES + 255) / 256, 256, 0, stream>>>(src, dst, cursor, srcs_csr);

    // embed: xsb[:,0:128] = x @ W_emb + b_emb  (fp32 A, K=64, direct path)
    gemm_l2_kernel<4, 64, 0, false, 2, false, false, false><<<gg2, 256, 0, stream>>>(
        x, nullptr, IN_DIM, wpk + OFF_EMB, b_emb,
        nullptr, 0, nullptr, nullptr, nullptr,
        nullptr, xsb, 512, nullptr,
        N_NODES, DIM, 0, nullptr, nullptr, nullptr, nullptr,
        nullptr, nullptr, nullptr, nullptr);

    for (int l = 0; l < LAYERS; l++) {
        const unsigned short* h_cur = xsb + (size_t)l * DIM;
        const float* hstats = l ? stats2 + (l - 1) * 256 : nullptr;
        const float* hg = l ? bn2_g + (l - 1) * DIM : nullptr;
        const float* hb = l ? bn2_b + (l - 1) * DIM : nullptr;
        // feat = BN2(h) @ gat_W -> bf16, fused el/er  (direct path)
        if (l == 0)
            gemm_l2_kernel<4, 128, 0, true, 2, true, false, false><<<gg2, 256, 0, stream>>>(
                nullptr, h_cur, 512, wpk + OFF_GAT + l * 16384, nullptr,
                nullptr, 0, nullptr, nullptr, nullptr,
                nullptr, featb, DIM, nullptr,
                N_NODES, DIM, 0, nullptr, nullptr, nullptr, nullptr,
                attn_l + l * DIM, attn_r + l * DIM, el, er);
        else
            gemm_l2_kernel<4, 128, 1, true, 2, true, false, false><<<gg2, 256, 0, stream>>>(
                nullptr, h_cur, 512, wpk + OFF_GAT + l * 16384, nullptr,
                nullptr, 0, nullptr, nullptr, nullptr,
                nullptr, featb, DIM, nullptr,
                N_NODES, DIM, 0, hstats, nullptr, hg, hb,
                attn_l + l * DIM, attn_r + l * DIM, el, er);
        // btb = BN2(h) + agg + bias  (pre-BN1, bf16); inline edge exp; fused BN1 rep-stats
        gat_aggregate_kernel<<<AGG_BLOCKS, 256, 0, stream>>>(
            featb, el, er, indptr, srcs_csr, h_cur, 512,
            hstats, hg, hb, gat_b + l * DIM, btb,
            rep1 + (size_t)l * NREP * 256);
        // FFN1: y1 = relu(BN1(btb) @ W1 + b1) -> bf16 ld224; AMODE=3 sums replicas (direct)
        gemm_l2_kernel<7, 128, 3, true, 2, false, false, false><<<gg2, 256, 0, stream>>>(
            nullptr, btb, DIM, wpk + OFF_W1 + l * 28672,
            ff_b1 + l * FF_DIM,
            nullptr, 0, nullptr, nullptr, nullptr,
            nullptr, y1b, 224, nullptr,
            N_NODES, FF_DIM, 1,
            rep1 + (size_t)l * NREP * 256, stats1c + l * 256,
            bn1_g + l * DIM, bn1_b + l * DIM,
            nullptr, nullptr, nullptr, nullptr);
        // FFN2: t = y1 @ W2 + b2 + BN1(btb) -> xsb block l+1 (bf16) + bn2 stats (direct)
        gemm_l2_kernel<4, 224, 0, true, 2, false, true, false><<<gg2, 256, 0, stream>>>(
            nullptr, y1b, 224, wpk + OFF_W2 + l * 28672,
            ff_b2 + l * DIM,
            btb, DIM, stats1c + l * 256, bn1_g + l * DIM, bn1_b + l * DIM,
            nullptr, xsb + (size_t)(l + 1) * DIM, 512, stats2 + l * 256,
            N_NODES, DIM, 0, nullptr, nullptr, nullptr, nullptr,
            nullptr, nullptr, nullptr, nullptr);
    }

    // dec: z = BN-affine-concat(xsb) @ dec_W1 (bf16 out) + dec stats
    // (MT=1, NT=4, 2 col-groups, KCH=128 chunked LDS-B + A-ring; ~22.6KB LDS)
    gemm_l2_kernel<4, 512, 2, true, 1, false, false, true><<<ggdec, 256, 0, stream>>>(
        nullptr, xsb, 512, wpk + OFF_DEC, nullptr,
        nullptr, 0, nullptr, nullptr, nullptr,
        nullptr, zb, DIM, statsD,
        N_NODES, DIM, 0, stats2, nullptr, bn2_g, bn2_b,
        nullptr, nullptr, nullptr, nullptr);
    decide_kernel<<<(N_NODES + 3) / 4, 256, 0, stream>>>(
        zb, statsD, dec_bn_g, dec_bn_b, dec_W2, outp, N_NODES);
}